// Round 11
// baseline (376.671 us; speedup 1.0000x reference)
//
#include <hip/hip_runtime.h>
#include <math.h>

#define BB   32      // batch
#define NN   1024    // nodes
#define DIN  2
#define DOUT 64
#define CIN  66      // DIN + DOUT
#define TD   32
#define ED   10
#define OG   128     // 2*DOUT (gate out)
#define OU   64      // upd out
#define KP   160     // padded K (132 real)
#define XTR  80      // XT rows per batch (68 data + 12 zero pad)
#define PS   88      // s_p stride (shorts)
#define SAS  168     // s_a / s_b K-stride (shorts)

typedef __bf16 bf16x8 __attribute__((ext_vector_type(8)));
typedef float  f32x4  __attribute__((ext_vector_type(4)));
typedef short  s16x8  __attribute__((ext_vector_type(8)));

__device__ __forceinline__ unsigned short f2b(float f) {
    __bf16 h = (__bf16)f;
    return *(unsigned short*)&h;
}

// ---------------------------------------------------------------------------
// K_PRE (R7-proven): heterogeneous preprocessing, one dispatch.
// ---------------------------------------------------------------------------
__global__ __launch_bounds__(256) void k_pre(
    const float* __restrict__ x, const float* __restrict__ state,
    const float* __restrict__ ne0, const float* __restrict__ ne1,
    const float* __restrict__ ne2,
    const float* __restrict__ w11, const float* __restrict__ b11,
    const float* __restrict__ w12, const float* __restrict__ b12,
    const float* __restrict__ w13, const float* __restrict__ b13,
    const float* __restrict__ w21, const float* __restrict__ b21,
    const float* __restrict__ w22, const float* __restrict__ b22,
    const float* __restrict__ w23, const float* __restrict__ b23,
    const float* __restrict__ gate_w, const float* __restrict__ gate_b,
    const float* __restrict__ upd_w, const float* __restrict__ upd_b,
    unsigned short* __restrict__ nv1b, unsigned short* __restrict__ nv2b,
    unsigned short* __restrict__ XT0, unsigned short* __restrict__ XT1,
    unsigned short* __restrict__ BcTg, unsigned short* __restrict__ BcTu,
    float* __restrict__ biasG, float* __restrict__ biasU)
{
    __shared__ float sw[2408];
    __shared__ unsigned short st[68*72];
    int blk = blockIdx.x;
    int t = threadIdx.x;

    if (blk < 128) {
        const int oW1 = 0, oB1 = 1056, oW2 = 1072, oB2 = 1104, oW3 = 1108, oB3 = 1172, F2 = 1204;
        for (int i = t; i < 1056; i += 256) { sw[oW1+i] = w11[i]; sw[F2+oW1+i] = w21[i]; }
        if (t < 16) { sw[oB1+t] = b11[t]; sw[F2+oB1+t] = b21[t]; }
        if (t < 32) { sw[oW2+t] = w12[t]; sw[F2+oW2+t] = w22[t]; }
        if (t < 2)  { sw[oB2+t] = b12[t]; sw[F2+oB2+t] = b22[t]; }
        if (t < 64) { sw[oW3+t] = w13[t]; sw[F2+oW3+t] = w23[t]; }
        if (t >= 64 && t < 96) { sw[oB3+t-64] = b13[t-64]; sw[F2+oB3+t-64] = b23[t-64]; }
        __syncthreads();

        int p = blk*256 + t;
        int b = p >> 10;

        float h1a[16], h1b[16];
        #pragma unroll
        for (int j = 0; j < 16; ++j) { h1a[j] = sw[oB1+j]; h1b[j] = sw[F2+oB1+j]; }
        for (int i = 0; i < CIN; ++i) {
            float v = (i < DIN) ? x[(size_t)p*DIN + i] : state[(size_t)p*DOUT + (i-DIN)];
            #pragma unroll
            for (int jq = 0; jq < 4; ++jq) {
                float4 wa = *(const float4*)&sw[oW1 + i*16 + jq*4];
                float4 wb = *(const float4*)&sw[F2 + oW1 + i*16 + jq*4];
                h1a[jq*4+0] += v*wa.x; h1a[jq*4+1] += v*wa.y;
                h1a[jq*4+2] += v*wa.z; h1a[jq*4+3] += v*wa.w;
                h1b[jq*4+0] += v*wb.x; h1b[jq*4+1] += v*wb.y;
                h1b[jq*4+2] += v*wb.z; h1b[jq*4+3] += v*wb.w;
            }
        }
        #pragma unroll
        for (int j = 0; j < 16; ++j) {
            h1a[j] = 1.f/(1.f + __expf(-h1a[j]));
            h1b[j] = 1.f/(1.f + __expf(-h1b[j]));
        }
        float h2a0 = sw[oB2+0], h2a1 = sw[oB2+1];
        float h2b0 = sw[F2+oB2+0], h2b1 = sw[F2+oB2+1];
        #pragma unroll
        for (int i = 0; i < 16; ++i) {
            h2a0 += h1a[i]*sw[oW2 + i*2 + 0];
            h2a1 += h1a[i]*sw[oW2 + i*2 + 1];
            h2b0 += h1b[i]*sw[F2+oW2 + i*2 + 0];
            h2b1 += h1b[i]*sw[F2+oW2 + i*2 + 1];
        }
        h2a0 = 1.f/(1.f + __expf(-h2a0)); h2a1 = 1.f/(1.f + __expf(-h2a1));
        h2b0 = 1.f/(1.f + __expf(-h2b0)); h2b1 = 1.f/(1.f + __expf(-h2b1));

        const float* pn0 = ne0 + b*TD;
        const float* pn1 = ne1 + b*TD;
        #pragma unroll
        for (int jq = 0; jq < 8; ++jq) {
            float4 ba  = *(const float4*)&sw[oB3 + jq*4];
            float4 wa0 = *(const float4*)&sw[oW3 + jq*4];
            float4 wa1 = *(const float4*)&sw[oW3 + 32 + jq*4];
            float4 bb2 = *(const float4*)&sw[F2+oB3 + jq*4];
            float4 wb0 = *(const float4*)&sw[F2+oW3 + jq*4];
            float4 wb1 = *(const float4*)&sw[F2+oW3 + 32 + jq*4];
            float4 n0 = *(const float4*)&pn0[jq*4];
            float4 n1 = *(const float4*)&pn1[jq*4];
            ushort4 u1, u2;
            u1.x = f2b(tanhf(n0.x*(ba.x + h2a0*wa0.x + h2a1*wa1.x)));
            u1.y = f2b(tanhf(n0.y*(ba.y + h2a0*wa0.y + h2a1*wa1.y)));
            u1.z = f2b(tanhf(n0.z*(ba.z + h2a0*wa0.z + h2a1*wa1.z)));
            u1.w = f2b(tanhf(n0.w*(ba.w + h2a0*wa0.w + h2a1*wa1.w)));
            u2.x = f2b(tanhf(n1.x*(bb2.x + h2b0*wb0.x + h2b1*wb1.x)));
            u2.y = f2b(tanhf(n1.y*(bb2.y + h2b0*wb0.y + h2b1*wb1.y)));
            u2.z = f2b(tanhf(n1.z*(bb2.z + h2b0*wb0.z + h2b1*wb1.z)));
            u2.w = f2b(tanhf(n1.w*(bb2.w + h2b0*wb0.w + h2b1*wb1.w)));
            *(ushort4*)&nv1b[(size_t)p*TD + jq*4] = u1;
            *(ushort4*)&nv2b[(size_t)p*TD + jq*4] = u2;
        }
    } else if (blk < 640) {
        int idx = blk - 128;
        int b = idx >> 4, m0 = (idx & 15)*64;
        for (int i = t; i < 1024; i += 256) {
            int m = i >> 4, cq = i & 15;
            size_t base = (size_t)b*NN + m0 + m;
            float4 v = *(const float4*)&state[base*DOUT + cq*4];
            st[(2 + cq*4 + 0)*72 + m] = f2b(v.x);
            st[(2 + cq*4 + 1)*72 + m] = f2b(v.y);
            st[(2 + cq*4 + 2)*72 + m] = f2b(v.z);
            st[(2 + cq*4 + 3)*72 + m] = f2b(v.w);
        }
        if (t < 128) {
            int m = t >> 1, c = t & 1;
            st[c*72 + m] = f2b(x[((size_t)b*NN + m0 + m)*DIN + c]);
        }
        __syncthreads();
        const unsigned int ONE2 = 0x3F803F80u;
        for (int i = t; i < XTR*8; i += 256) {
            int c = i >> 3, ch = i & 7;
            uint4 v;
            if (c < 66)      v = *(const uint4*)&st[c*72 + ch*8];
            else if (c == 66) v = make_uint4(ONE2, ONE2, ONE2, ONE2);
            else              v = make_uint4(0, 0, 0, 0);
            *(uint4*)&XT0[((size_t)b*XTR + c)*NN + m0 + ch*8] = v;
            if (c < 2 || c >= 66)
                *(uint4*)&XT1[((size_t)b*XTR + c)*NN + m0 + ch*8] = v;
        }
    } else if (blk < 1840) {
        int tid = (blk - 640)*256 + t;
        int c = tid / KP, k = tid - c*KP;
        const float* pool; int O, cc; unsigned short* dst;
        if (c < 1280) { pool = gate_w; O = OG; cc = c;        dst = BcTg; }
        else          { pool = upd_w;  O = OU; cc = c - 1280; dst = BcTu; }
        int d = cc / O, o = cc - d*O;
        float v = 0.f;
        if (k < 132) {
            int kp = (k < 66) ? 0 : 1;
            int i  = (k < 66) ? k : k - 66;
            v = pool[(size_t)((d*4 + kp)*CIN + i)*O + o]
              + pool[(size_t)((d*4 + kp + 2)*CIN + i)*O + o];
        }
        dst[(size_t)cc*KP + k] = f2b(v);
    } else {
        int i = (blk - 1840)*256 + t;
        int n = i / 192, j = i - n*192;
        float v = 0.f;
        if (j < 128) {
            #pragma unroll
            for (int d = 0; d < ED; ++d) v += ne2[(size_t)n*ED + d]*gate_b[d*OG + j];
            biasG[(size_t)n*OG + j] = v;
        } else {
            int o = j - 128;
            #pragma unroll
            for (int d = 0; d < ED; ++d) v += ne2[(size_t)n*ED + d]*upd_b[d*OU + o];
            biasU[(size_t)n*OU + o] = v;
        }
    }
}

// ---------------------------------------------------------------------------
// K_FUSED<O,MODE>: aapply (R10-proven 512-thread paired-wave body) + einsum
// GEMM on the block's own 64 A-rows (A lives only in LDS).
//   Phase A: S = nv1.nv2^T - nv2.nv1^T, relu, PV accumulate (ones-col rowsum).
//   Build:   s_a[64][168] = [X(66) | AX(66) | 0 pad], bf16.
//   Phase G: 8 waves = 2 rowgroups(32r) x 4 o-slice lanes; B in 2-d chunks
//            (4 slices x 32cc x 336B = 42 KB); acc[10] in regs -> d-contract
//            epilogue: MODE0 sigmoid -> XT1 z-rows / rbuf; MODE1 tanh+GRU -> out.
// XCD swizzle: b = blockIdx&31 -> all row-blocks of batch b on XCD b%8.
// ---------------------------------------------------------------------------
template<int O, int MODE>
__global__ __launch_bounds__(512) void k_fused(
    const unsigned short* __restrict__ nv1b, const unsigned short* __restrict__ nv2b,
    const unsigned short* __restrict__ XTg, const unsigned short* __restrict__ BcT,
    const float* __restrict__ ne2, const float* __restrict__ biasP,
    const float* __restrict__ state, unsigned short* __restrict__ XT1,
    float* __restrict__ rbuf, float* __restrict__ out)
{
    union SM {
        struct {
            unsigned short nv1r[64*40], nv2r[64*40], nv1c[64*40], nv2c[64*40];
            unsigned short p[64*PS];
            unsigned short xt[80*72];
            float rs[64];
        } aa;                                   // 43.5 KB
        struct {
            unsigned short a[64*SAS];           // 21.5 KB
            unsigned short bb[4][32*SAS];       // 43.0 KB
        } ge;                                   // 64.5 KB (union size)
    };
    __shared__ SM sm;

    int t = threadIdx.x;
    int id = blockIdx.x;
    int b = id & 31, rbase = (id >> 5)*64;
    int w = t >> 6, lane = t & 63, lq = lane >> 4, ln = lane & 15;
    int g = w >> 1, sub = w & 1;

    // ---------------- Phase A: fused A-apply (R10-proven) ----------------
    {
        int arr = t >> 8, j = t & 255;
        int node = j >> 2, ch = j & 3;
        const unsigned short* src = (arr ? nv2b : nv1b)
            + ((size_t)b*NN + rbase + node)*TD + ch*8;
        unsigned short* dst = (arr ? sm.aa.nv2r : sm.aa.nv1r) + node*40 + ch*8;
        *(uint4*)dst = *(const uint4*)src;
    }
    __syncthreads();

    bf16x8 a1 = *(const bf16x8*)&sm.aa.nv1r[(16*g + ln)*40 + lq*8];
    s16x8 a2s = *(const s16x8*)&sm.aa.nv2r[(16*g + ln)*40 + lq*8];
    const s16x8 sgn = {(short)0x8000,(short)0x8000,(short)0x8000,(short)0x8000,
                       (short)0x8000,(short)0x8000,(short)0x8000,(short)0x8000};
    a2s ^= sgn;
    bf16x8 a2n = (bf16x8)a2s;

    f32x4 acc[3];
    #pragma unroll
    for (int i = 0; i < 3; ++i) acc[i] = (f32x4){0.f,0.f,0.f,0.f};
    const f32x4 zero4 = {0.f,0.f,0.f,0.f};

    for (int mb = 0; mb < NN; mb += 64) {
        __syncthreads();
        {
            int arr = t >> 8, j = t & 255;
            int node = j >> 2, ch = j & 3;
            const unsigned short* src = (arr ? nv2b : nv1b)
                + ((size_t)b*NN + mb + node)*TD + ch*8;
            unsigned short* dst = (arr ? sm.aa.nv2c : sm.aa.nv1c) + node*40 + ch*8;
            *(uint4*)dst = *(const uint4*)src;
        }
        for (int i = t; i < 640; i += 512) {
            int c = i >> 3, ch = i & 7;
            *(uint4*)&sm.aa.xt[c*72 + ch*8] =
                *(const uint4*)&XTg[((size_t)b*XTR + c)*NN + mb + ch*8];
        }
        __syncthreads();

        #pragma unroll
        for (int jj = 0; jj < 2; ++jj) {
            int j0 = (sub*2 + jj)*16;
            bf16x8 b2 = *(const bf16x8*)&sm.aa.nv2c[(j0 + ln)*40 + lq*8];
            bf16x8 b1 = *(const bf16x8*)&sm.aa.nv1c[(j0 + ln)*40 + lq*8];
            f32x4 s = __builtin_amdgcn_mfma_f32_16x16x32_bf16(a1,  b2, zero4, 0, 0, 0);
            s       = __builtin_amdgcn_mfma_f32_16x16x32_bf16(a2n, b1, s,     0, 0, 0);
            #pragma unroll
            for (int r = 0; r < 4; ++r) {
                float p = fmaxf(s[r], 0.f);
                *(__bf16*)&sm.aa.p[(16*g + lq*4 + r)*PS + j0 + ln] = (__bf16)p;
            }
        }
        __syncthreads();

        bf16x8 pa0 = *(const bf16x8*)&sm.aa.p[(16*g + ln)*PS +      lq*8];
        bf16x8 pa1 = *(const bf16x8*)&sm.aa.p[(16*g + ln)*PS + 32 + lq*8];
        if (sub == 0) {
            #pragma unroll
            for (int k = 0; k < 3; ++k) {
                int n0 = k*16;
                bf16x8 xb0 = *(const bf16x8*)&sm.aa.xt[(n0 + ln)*72 +      lq*8];
                bf16x8 xb1 = *(const bf16x8*)&sm.aa.xt[(n0 + ln)*72 + 32 + lq*8];
                acc[k] = __builtin_amdgcn_mfma_f32_16x16x32_bf16(pa0, xb0, acc[k], 0, 0, 0);
                acc[k] = __builtin_amdgcn_mfma_f32_16x16x32_bf16(pa1, xb1, acc[k], 0, 0, 0);
            }
        } else {
            #pragma unroll
            for (int k = 0; k < 2; ++k) {
                int n0 = (3 + k)*16;
                bf16x8 xb0 = *(const bf16x8*)&sm.aa.xt[(n0 + ln)*72 +      lq*8];
                bf16x8 xb1 = *(const bf16x8*)&sm.aa.xt[(n0 + ln)*72 + 32 + lq*8];
                acc[k] = __builtin_amdgcn_mfma_f32_16x16x32_bf16(pa0, xb0, acc[k], 0, 0, 0);
                acc[k] = __builtin_amdgcn_mfma_f32_16x16x32_bf16(pa1, xb1, acc[k], 0, 0, 0);
            }
        }
    }

    if (sub == 1 && ln == 2) {
        #pragma unroll
        for (int r = 0; r < 4; ++r) sm.aa.rs[16*g + lq*4 + r] = acc[1][r];
    }
    __syncthreads();
    float rinv[4];
    #pragma unroll
    for (int r = 0; r < 4; ++r) rinv[r] = 1.0f / (1.0f + sm.aa.rs[16*g + lq*4 + r]);
    __syncthreads();                            // rs consumed; LDS may be reused

    // ---------------- Build s_a = [X | AX | 0] ----------------
    {
        int kmax = sub ? 2 : 3;
        for (int k = 0; k < kmax; ++k) {
            int c = (sub ? (3 + k) : k)*16 + ln;
            if (c < CIN) {
                #pragma unroll
                for (int r = 0; r < 4; ++r) {
                    int row_l = 16*g + lq*4 + r;
                    int gr = rbase + row_l;
                    unsigned short xu = XTg[((size_t)b*XTR + c)*NN + gr];
                    float xr = (float)(*(const __bf16*)&xu);
                    sm.ge.a[row_l*SAS + c]      = xu;
                    sm.ge.a[row_l*SAS + 66 + c] = f2b((acc[k][r] + xr) * rinv[r]);
                }
            }
        }
        for (int i = t; i < 64*36; i += 512) {  // zero cols 132..167
            int row = i / 36, cc = 132 + (i - 36*(i/36));
            sm.ge.a[row*SAS + cc] = 0;
        }
    }

    // ---------------- Phase G: einsum GEMM on own 64 rows ----------------
    const int rg = w >> 2;                      // rowgroup: rows 32rg..32rg+31
    const int sl = w & 3;                       // o-slice lane
    const int ITERS = O/16/4;                   // gate 2, upd 1

    for (int iter = 0; iter < ITERS; ++iter) {
        int o0 = (iter*4 + sl)*16;
        int o = o0 + ln;

        f32x4 gacc[ED][2];
        #pragma unroll
        for (int d = 0; d < ED; ++d) {
            gacc[d][0] = (f32x4){0.f,0.f,0.f,0.f};
            gacc[d][1] = (f32x4){0.f,0.f,0.f,0.f};
        }

        for (int chunk = 0; chunk < 5; ++chunk) {
            __syncthreads();                    // bb safe to overwrite / s_a built
            for (int i = t; i < 2560; i += 512) {
                int isl = i / 640, rem = i - isl*640;
                int cc = rem / 20, kc = rem - cc*20;
                int d = chunk*2 + (cc >> 4), oo = cc & 15;
                int o0s = (iter*4 + isl)*16;
                *(uint4*)&sm.ge.bb[isl][cc*SAS + kc*8] =
                    *(const uint4*)&BcT[(size_t)(d*O + o0s + oo)*KP + kc*8];
            }
            __syncthreads();

            #pragma unroll
            for (int kc = 0; kc < 5; ++kc) {
                bf16x8 af0 = *(const bf16x8*)&sm.ge.a[(rg*32      + ln)*SAS + kc*32 + lq*8];
                bf16x8 af1 = *(const bf16x8*)&sm.ge.a[(rg*32 + 16 + ln)*SAS + kc*32 + lq*8];
                #pragma unroll
                for (int ctl = 0; ctl < 2; ++ctl) {
                    int d = chunk*2 + ctl;
                    bf16x8 bf = *(const bf16x8*)&sm.ge.bb[sl][(ctl*16 + ln)*SAS + kc*32 + lq*8];
                    gacc[d][0] = __builtin_amdgcn_mfma_f32_16x16x32_bf16(af0, bf, gacc[d][0], 0, 0, 0);
                    gacc[d][1] = __builtin_amdgcn_mfma_f32_16x16x32_bf16(af1, bf, gacc[d][1], 0, 0, 0);
                }
            }
        }

        #pragma unroll
        for (int f = 0; f < 2; ++f) {
            #pragma unroll
            for (int r = 0; r < 4; ++r) {
                int row_l = rg*32 + 16*f + lq*4 + r;
                int n = rbase + row_l;
                size_t rowG = (size_t)b*NN + n;
                const float* nep = &ne2[(size_t)n*ED];
                float val = biasP[(size_t)n*O + o];
                #pragma unroll
                for (int d = 0; d < ED; ++d)
                    val += nep[d] * gacc[d][f][r];
                if (MODE == 0) {
                    float sv = 1.f/(1.f + __expf(-val));
                    if (o0 < 64) {
                        float zst = sv * state[rowG*DOUT + o];
                        XT1[((size_t)b*XTR + 2 + o)*NN + n] = f2b(zst);
                    } else {
                        rbuf[rowG*DOUT + (o - 64)] = sv;
                    }
                } else {
                    float hc = tanhf(val);
                    float rg2 = rbuf[rowG*DOUT + o];
                    float st = state[rowG*DOUT + o];
                    out[rowG*DOUT + o] = rg2*st + (1.f - rg2)*hc;
                }
            }
        }
    }
}

// ---------------------------------------------------------------------------
extern "C" void kernel_launch(void* const* d_in, const int* in_sizes, int n_in,
                              void* d_out, int out_size, void* d_ws, size_t ws_size,
                              hipStream_t stream)
{
    const float* x      = (const float*)d_in[0];
    const float* state  = (const float*)d_in[1];
    const float* ne0    = (const float*)d_in[2];
    const float* ne1    = (const float*)d_in[3];
    const float* ne2    = (const float*)d_in[4];
    const float* f1w1   = (const float*)d_in[5];
    const float* f1b1   = (const float*)d_in[6];
    const float* f1w2   = (const float*)d_in[7];
    const float* f1b2   = (const float*)d_in[8];
    const float* f1w3   = (const float*)d_in[9];
    const float* f1b3   = (const float*)d_in[10];
    const float* f2w1   = (const float*)d_in[11];
    const float* f2b1   = (const float*)d_in[12];
    const float* f2w2   = (const float*)d_in[13];
    const float* f2b2   = (const float*)d_in[14];
    const float* f2w3   = (const float*)d_in[15];
    const float* f2b3   = (const float*)d_in[16];
    const float* gate_w = (const float*)d_in[17];
    const float* gate_b = (const float*)d_in[18];
    const float* upd_w  = (const float*)d_in[19];
    const float* upd_b  = (const float*)d_in[20];

    unsigned short* nv1b = (unsigned short*)d_ws;
    unsigned short* nv2b = nv1b + (size_t)BB*NN*TD;
    unsigned short* XT0  = nv2b + (size_t)BB*NN*TD;
    unsigned short* XT1  = XT0  + (size_t)BB*XTR*NN;
    unsigned short* BcTg = XT1  + (size_t)BB*XTR*NN;
    unsigned short* BcTu = BcTg + (size_t)1280*KP;
    float* biasG = (float*)(BcTu + (size_t)640*KP);
    float* biasU = biasG + (size_t)NN*OG;
    float* rbuf  = biasU + (size_t)NN*OU;
    float* out   = (float*)d_out;

    k_pre<<<dim3(2608), 256, 0, stream>>>(x, state, ne0, ne1, ne2,
        f1w1, f1b1, f1w2, f1b2, f1w3, f1b3,
        f2w1, f2b1, f2w2, f2b2, f2w3, f2b3,
        gate_w, gate_b, upd_w, upd_b,
        nv1b, nv2b, XT0, XT1, BcTg, BcTu, biasG, biasU);

    k_fused<OG,0><<<dim3(512), 512, 0, stream>>>(nv1b, nv2b, XT0, BcTg,
        ne2, biasG, state, XT1, rbuf, nullptr);

    k_fused<OU,1><<<dim3(512), 512, 0, stream>>>(nv1b, nv2b, XT1, BcTu,
        ne2, biasU, state, nullptr, rbuf, out);
}

// Round 12
// 236.574 us; speedup vs baseline: 1.5922x; 1.5922x over previous
//
#include <hip/hip_runtime.h>
#include <math.h>

#define BB   32      // batch
#define NN   1024    // nodes
#define DIN  2
#define DOUT 64
#define CIN  66      // DIN + DOUT
#define TD   32
#define ED   10
#define OG   128     // 2*DOUT (gate out)
#define OU   64      // upd out
#define KP   160     // padded K for the einsum GEMM (132 real)
#define XTR  80      // XT rows per batch (68 data + 12 zero pad)
#define PS   88      // s_p stride (shorts): 16B-aligned, 2-way banks only

typedef __bf16 bf16x8 __attribute__((ext_vector_type(8)));
typedef float  f32x4  __attribute__((ext_vector_type(4)));
typedef short  s16x8  __attribute__((ext_vector_type(8)));

__device__ __forceinline__ unsigned short f2b(float f) {
    __bf16 h = (__bf16)f;
    return *(unsigned short*)&h;
}

// ---------------------------------------------------------------------------
// K_PRE: heterogeneous preprocessing, one dispatch.
//   blocks [0,128):    nv MLPs
//   blocks [128,640):  XT0 build + XT1 static rows
//   blocks [640,1840): BcT combined weights (o-fast mapping: coalesced pool reads)
//   blocks [1840,2608): bias precompute
// ---------------------------------------------------------------------------
__global__ __launch_bounds__(256) void k_pre(
    const float* __restrict__ x, const float* __restrict__ state,
    const float* __restrict__ ne0, const float* __restrict__ ne1,
    const float* __restrict__ ne2,
    const float* __restrict__ w11, const float* __restrict__ b11,
    const float* __restrict__ w12, const float* __restrict__ b12,
    const float* __restrict__ w13, const float* __restrict__ b13,
    const float* __restrict__ w21, const float* __restrict__ b21,
    const float* __restrict__ w22, const float* __restrict__ b22,
    const float* __restrict__ w23, const float* __restrict__ b23,
    const float* __restrict__ gate_w, const float* __restrict__ gate_b,
    const float* __restrict__ upd_w, const float* __restrict__ upd_b,
    unsigned short* __restrict__ nv1b, unsigned short* __restrict__ nv2b,
    unsigned short* __restrict__ XT0, unsigned short* __restrict__ XT1,
    unsigned short* __restrict__ BcTg, unsigned short* __restrict__ BcTu,
    float* __restrict__ biasG, float* __restrict__ biasU)
{
    __shared__ float sw[2408];
    __shared__ unsigned short st[68*72];
    int blk = blockIdx.x;
    int t = threadIdx.x;

    if (blk < 128) {
        const int oW1 = 0, oB1 = 1056, oW2 = 1072, oB2 = 1104, oW3 = 1108, oB3 = 1172, F2 = 1204;
        for (int i = t; i < 1056; i += 256) { sw[oW1+i] = w11[i]; sw[F2+oW1+i] = w21[i]; }
        if (t < 16) { sw[oB1+t] = b11[t]; sw[F2+oB1+t] = b21[t]; }
        if (t < 32) { sw[oW2+t] = w12[t]; sw[F2+oW2+t] = w22[t]; }
        if (t < 2)  { sw[oB2+t] = b12[t]; sw[F2+oB2+t] = b22[t]; }
        if (t < 64) { sw[oW3+t] = w13[t]; sw[F2+oW3+t] = w23[t]; }
        if (t >= 64 && t < 96) { sw[oB3+t-64] = b13[t-64]; sw[F2+oB3+t-64] = b23[t-64]; }
        __syncthreads();

        int p = blk*256 + t;
        int b = p >> 10;

        float h1a[16], h1b[16];
        #pragma unroll
        for (int j = 0; j < 16; ++j) { h1a[j] = sw[oB1+j]; h1b[j] = sw[F2+oB1+j]; }
        for (int i = 0; i < CIN; ++i) {
            float v = (i < DIN) ? x[(size_t)p*DIN + i] : state[(size_t)p*DOUT + (i-DIN)];
            #pragma unroll
            for (int jq = 0; jq < 4; ++jq) {
                float4 wa = *(const float4*)&sw[oW1 + i*16 + jq*4];
                float4 wb = *(const float4*)&sw[F2 + oW1 + i*16 + jq*4];
                h1a[jq*4+0] += v*wa.x; h1a[jq*4+1] += v*wa.y;
                h1a[jq*4+2] += v*wa.z; h1a[jq*4+3] += v*wa.w;
                h1b[jq*4+0] += v*wb.x; h1b[jq*4+1] += v*wb.y;
                h1b[jq*4+2] += v*wb.z; h1b[jq*4+3] += v*wb.w;
            }
        }
        #pragma unroll
        for (int j = 0; j < 16; ++j) {
            h1a[j] = 1.f/(1.f + __expf(-h1a[j]));
            h1b[j] = 1.f/(1.f + __expf(-h1b[j]));
        }
        float h2a0 = sw[oB2+0], h2a1 = sw[oB2+1];
        float h2b0 = sw[F2+oB2+0], h2b1 = sw[F2+oB2+1];
        #pragma unroll
        for (int i = 0; i < 16; ++i) {
            h2a0 += h1a[i]*sw[oW2 + i*2 + 0];
            h2a1 += h1a[i]*sw[oW2 + i*2 + 1];
            h2b0 += h1b[i]*sw[F2+oW2 + i*2 + 0];
            h2b1 += h1b[i]*sw[F2+oW2 + i*2 + 1];
        }
        h2a0 = 1.f/(1.f + __expf(-h2a0)); h2a1 = 1.f/(1.f + __expf(-h2a1));
        h2b0 = 1.f/(1.f + __expf(-h2b0)); h2b1 = 1.f/(1.f + __expf(-h2b1));

        const float* pn0 = ne0 + b*TD;
        const float* pn1 = ne1 + b*TD;
        #pragma unroll
        for (int jq = 0; jq < 8; ++jq) {
            float4 ba  = *(const float4*)&sw[oB3 + jq*4];
            float4 wa0 = *(const float4*)&sw[oW3 + jq*4];
            float4 wa1 = *(const float4*)&sw[oW3 + 32 + jq*4];
            float4 bb2 = *(const float4*)&sw[F2+oB3 + jq*4];
            float4 wb0 = *(const float4*)&sw[F2+oW3 + jq*4];
            float4 wb1 = *(const float4*)&sw[F2+oW3 + 32 + jq*4];
            float4 n0 = *(const float4*)&pn0[jq*4];
            float4 n1 = *(const float4*)&pn1[jq*4];
            ushort4 u1, u2;
            u1.x = f2b(tanhf(n0.x*(ba.x + h2a0*wa0.x + h2a1*wa1.x)));
            u1.y = f2b(tanhf(n0.y*(ba.y + h2a0*wa0.y + h2a1*wa1.y)));
            u1.z = f2b(tanhf(n0.z*(ba.z + h2a0*wa0.z + h2a1*wa1.z)));
            u1.w = f2b(tanhf(n0.w*(ba.w + h2a0*wa0.w + h2a1*wa1.w)));
            u2.x = f2b(tanhf(n1.x*(bb2.x + h2b0*wb0.x + h2b1*wb1.x)));
            u2.y = f2b(tanhf(n1.y*(bb2.y + h2b0*wb0.y + h2b1*wb1.y)));
            u2.z = f2b(tanhf(n1.z*(bb2.z + h2b0*wb0.z + h2b1*wb1.z)));
            u2.w = f2b(tanhf(n1.w*(bb2.w + h2b0*wb0.w + h2b1*wb1.w)));
            *(ushort4*)&nv1b[(size_t)p*TD + jq*4] = u1;
            *(ushort4*)&nv2b[(size_t)p*TD + jq*4] = u2;
        }
    } else if (blk < 640) {
        int idx = blk - 128;
        int b = idx >> 4, m0 = (idx & 15)*64;
        for (int i = t; i < 1024; i += 256) {
            int m = i >> 4, cq = i & 15;
            size_t base = (size_t)b*NN + m0 + m;
            float4 v = *(const float4*)&state[base*DOUT + cq*4];
            st[(2 + cq*4 + 0)*72 + m] = f2b(v.x);
            st[(2 + cq*4 + 1)*72 + m] = f2b(v.y);
            st[(2 + cq*4 + 2)*72 + m] = f2b(v.z);
            st[(2 + cq*4 + 3)*72 + m] = f2b(v.w);
        }
        if (t < 128) {
            int m = t >> 1, c = t & 1;
            st[c*72 + m] = f2b(x[((size_t)b*NN + m0 + m)*DIN + c]);
        }
        __syncthreads();
        const unsigned int ONE2 = 0x3F803F80u;
        for (int i = t; i < XTR*8; i += 256) {
            int c = i >> 3, ch = i & 7;
            uint4 v;
            if (c < 66)      v = *(const uint4*)&st[c*72 + ch*8];
            else if (c == 66) v = make_uint4(ONE2, ONE2, ONE2, ONE2);
            else              v = make_uint4(0, 0, 0, 0);
            *(uint4*)&XT0[((size_t)b*XTR + c)*NN + m0 + ch*8] = v;
            if (c < 2 || c >= 66)
                *(uint4*)&XT1[((size_t)b*XTR + c)*NN + m0 + ch*8] = v;
        }
    } else if (blk < 1840) {
        // o-fast mapping: c = tid%1920 (fast) -> pool reads coalesced over o
        int tid = (blk - 640)*256 + t;            // < 160*1920
        int k = tid / 1920, c = tid - k*1920;
        const float* pool; int O, cc; unsigned short* dst;
        if (c < 1280) { pool = gate_w; O = OG; cc = c;        dst = BcTg; }
        else          { pool = upd_w;  O = OU; cc = c - 1280; dst = BcTu; }
        int d = cc / O, o = cc - d*O;
        float v = 0.f;
        if (k < 132) {
            int kp = (k < 66) ? 0 : 1;
            int i  = (k < 66) ? k : k - 66;
            v = pool[(size_t)((d*4 + kp)*CIN + i)*O + o]
              + pool[(size_t)((d*4 + kp + 2)*CIN + i)*O + o];
        }
        dst[(size_t)cc*KP + k] = f2b(v);
    } else {
        int i = (blk - 1840)*256 + t;
        int n = i / 192, j = i - n*192;
        float v = 0.f;
        if (j < 128) {
            #pragma unroll
            for (int d = 0; d < ED; ++d) v += ne2[(size_t)n*ED + d]*gate_b[d*OG + j];
            biasG[(size_t)n*OG + j] = v;
        } else {
            int o = j - 128;
            #pragma unroll
            for (int d = 0; d < ED; ++d) v += ne2[(size_t)n*ED + d]*upd_b[d*OU + o];
            biasU[(size_t)n*OU + o] = v;
        }
    }
}

// ---------------------------------------------------------------------------
// K_AAPPLY v7: 512 threads, paired waves (R10-proven compute), now 2 barriers
// per iter via LDS double-buffered col staging:
//   per iter: [S_it]  sync  [PV_it ; stage_{it+1} -> other buffer]  sync
// PV precedes staging in program order so PV ds_reads aren't queued behind the
// staging vmcnt; staging latency lands at the barrier, hidden by other waves.
// ---------------------------------------------------------------------------
__global__ __launch_bounds__(512) void k_aapply(
    const unsigned short* __restrict__ nv1b, const unsigned short* __restrict__ nv2b,
    const unsigned short* __restrict__ XTg, unsigned short* __restrict__ A)
{
    __shared__ unsigned short s_nv1r[64*40], s_nv2r[64*40];       // 10.2 KB
    __shared__ unsigned short s_nv1c[2][64*40], s_nv2c[2][64*40]; // 20.5 KB
    __shared__ unsigned short s_p[64*PS];                         // 11.3 KB
    __shared__ unsigned short s_xt[2][80*72];                     // 23.0 KB
    __shared__ float s_rs[64];

    int t = threadIdx.x;
    int id = blockIdx.x;
    int b = id & 31, rbase = (id >> 5)*64;     // XCD-aligned: batch b -> XCD b%8
    int w = t >> 6, lane = t & 63, lq = lane >> 4, ln = lane & 15;
    int g = w >> 1, sub = w & 1;

    {   // row nv staging: 512 items, one per thread
        int arr = t >> 8, j = t & 255;
        int node = j >> 2, ch = j & 3;
        const unsigned short* src = (arr ? nv2b : nv1b)
            + ((size_t)b*NN + rbase + node)*TD + ch*8;
        unsigned short* dst = (arr ? s_nv2r : s_nv1r) + node*40 + ch*8;
        *(uint4*)dst = *(const uint4*)src;
    }
    {   // tile 0 col nv -> buf 0
        int arr = t >> 8, j = t & 255;
        int node = j >> 2, ch = j & 3;
        const unsigned short* src = (arr ? nv2b : nv1b)
            + ((size_t)b*NN + node)*TD + ch*8;
        unsigned short* dst = (arr ? s_nv2c[0] : s_nv1c[0]) + node*40 + ch*8;
        *(uint4*)dst = *(const uint4*)src;
    }
    for (int i = t; i < 640; i += 512) {       // tile 0 xt -> buf 0
        int c = i >> 3, ch = i & 7;
        *(uint4*)&s_xt[0][c*72 + ch*8] =
            *(const uint4*)&XTg[((size_t)b*XTR + c)*NN + ch*8];
    }
    __syncthreads();

    bf16x8 a1 = *(const bf16x8*)&s_nv1r[(16*g + ln)*40 + lq*8];
    s16x8 a2s = *(const s16x8*)&s_nv2r[(16*g + ln)*40 + lq*8];
    const s16x8 sgn = {(short)0x8000,(short)0x8000,(short)0x8000,(short)0x8000,
                       (short)0x8000,(short)0x8000,(short)0x8000,(short)0x8000};
    a2s ^= sgn;
    bf16x8 a2n = (bf16x8)a2s;

    f32x4 acc[3];                              // sub0 uses 3, sub1 uses 2
    #pragma unroll
    for (int i = 0; i < 3; ++i) acc[i] = (f32x4){0.f,0.f,0.f,0.f};
    const f32x4 zero4 = {0.f,0.f,0.f,0.f};

    for (int it = 0; it < 16; ++it) {
        int buf = it & 1;

        // ---- phase 1: S_it (reads nv_c[buf], writes s_p)
        #pragma unroll
        for (int jj = 0; jj < 2; ++jj) {
            int j0 = (sub*2 + jj)*16;
            bf16x8 b2 = *(const bf16x8*)&s_nv2c[buf][(j0 + ln)*40 + lq*8];
            bf16x8 b1 = *(const bf16x8*)&s_nv1c[buf][(j0 + ln)*40 + lq*8];
            f32x4 s = __builtin_amdgcn_mfma_f32_16x16x32_bf16(a1,  b2, zero4, 0, 0, 0);
            s       = __builtin_amdgcn_mfma_f32_16x16x32_bf16(a2n, b1, s,     0, 0, 0);
            #pragma unroll
            for (int r = 0; r < 4; ++r) {
                float p = fmaxf(s[r], 0.f);
                *(__bf16*)&s_p[(16*g + lq*4 + r)*PS + j0 + ln] = (__bf16)p;
            }
        }
        __syncthreads();                       // p visible; nv_c[buf^1]/xt[buf^1] free

        // ---- phase 2: PV_it (reads p, xt[buf]) then stage_{it+1} -> buf^1
        bf16x8 pa0 = *(const bf16x8*)&s_p[(16*g + ln)*PS +      lq*8];
        bf16x8 pa1 = *(const bf16x8*)&s_p[(16*g + ln)*PS + 32 + lq*8];
        if (sub == 0) {
            #pragma unroll
            for (int k = 0; k < 3; ++k) {
                int n0 = k*16;
                bf16x8 xb0 = *(const bf16x8*)&s_xt[buf][(n0 + ln)*72 +      lq*8];
                bf16x8 xb1 = *(const bf16x8*)&s_xt[buf][(n0 + ln)*72 + 32 + lq*8];
                acc[k] = __builtin_amdgcn_mfma_f32_16x16x32_bf16(pa0, xb0, acc[k], 0, 0, 0);
                acc[k] = __builtin_amdgcn_mfma_f32_16x16x32_bf16(pa1, xb1, acc[k], 0, 0, 0);
            }
        } else {
            #pragma unroll
            for (int k = 0; k < 2; ++k) {
                int n0 = (3 + k)*16;
                bf16x8 xb0 = *(const bf16x8*)&s_xt[buf][(n0 + ln)*72 +      lq*8];
                bf16x8 xb1 = *(const bf16x8*)&s_xt[buf][(n0 + ln)*72 + 32 + lq*8];
                acc[k] = __builtin_amdgcn_mfma_f32_16x16x32_bf16(pa0, xb0, acc[k], 0, 0, 0);
                acc[k] = __builtin_amdgcn_mfma_f32_16x16x32_bf16(pa1, xb1, acc[k], 0, 0, 0);
            }
        }

        if (it < 15) {
            int mbn = (it + 1)*64;
            int nbuf = buf ^ 1;
            {
                int arr = t >> 8, j = t & 255;
                int node = j >> 2, ch = j & 3;
                const unsigned short* src = (arr ? nv2b : nv1b)
                    + ((size_t)b*NN + mbn + node)*TD + ch*8;
                unsigned short* dst = (arr ? s_nv2c[nbuf] : s_nv1c[nbuf]) + node*40 + ch*8;
                *(uint4*)dst = *(const uint4*)src;
            }
            for (int i = t; i < 640; i += 512) {
                int c = i >> 3, ch = i & 7;
                *(uint4*)&s_xt[nbuf][c*72 + ch*8] =
                    *(const uint4*)&XTg[((size_t)b*XTR + c)*NN + mbn + ch*8];
            }
        }
        __syncthreads();                       // staged visible; p free for S_{it+1}
    }

    // rowsum = out col 66 -> sub1 tile 1, lane col ln==2
    if (sub == 1 && ln == 2) {
        #pragma unroll
        for (int r = 0; r < 4; ++r) s_rs[16*g + lq*4 + r] = acc[1][r];
    }
    __syncthreads();
    float rinv[4];
    #pragma unroll
    for (int r = 0; r < 4; ++r) rinv[r] = 1.0f / (1.0f + s_rs[16*g + lq*4 + r]);

    int kmax = sub ? 2 : 3;
    for (int k = 0; k < kmax; ++k) {
        int c = (sub ? (3 + k) : k)*16 + ln;
        if (c < CIN) {
            #pragma unroll
            for (int r = 0; r < 4; ++r) {
                int gr = rbase + 16*g + lq*4 + r;
                size_t rowG = (size_t)b*NN + gr;
                unsigned short xu = XTg[((size_t)b*XTR + c)*NN + gr];
                float xr = (float)(*(const __bf16*)&xu);
                A[rowG*KP + c]      = xu;
                A[rowG*KP + 66 + c] = f2b((acc[k][r] + xr) * rinv[r]);
            }
        }
    }
    for (int i = t; i < 64*28; i += 512) {
        int rr = i / 28, cc = 132 + (i - 28*(i/28));
        A[((size_t)b*NN + rbase + rr)*KP + cc] = 0;
    }
}

// ---------------------------------------------------------------------------
// K_GEMM v5 (R7/R10-proven): half-B resident (26.9 KB), two halves with
// restage barriers; ne2/bias direct from global; wave = 32 rows.
// ---------------------------------------------------------------------------
template<int O, int MODE>
__global__ __launch_bounds__(256) void k_gemm(
    const unsigned short* __restrict__ A, const unsigned short* __restrict__ BcT,
    const float* __restrict__ ne2, const float* __restrict__ biasP,
    const float* __restrict__ state, unsigned short* __restrict__ XT1,
    float* __restrict__ rbuf, float* __restrict__ out)
{
    __shared__ unsigned short s_b[80*168];

    int t = threadIdx.x;
    int w = t >> 6, lane = t & 63, lq = lane >> 4, ln = lane & 15;
    int o0 = blockIdx.y*16;
    int rowBlock = blockIdx.x*128;
    int rowW = rowBlock + w*32;

    f32x4 acc[2][2][5];
    #pragma unroll
    for (int h = 0; h < 2; ++h)
        #pragma unroll
        for (int f = 0; f < 2; ++f)
            #pragma unroll
            for (int c = 0; c < 5; ++c) acc[h][f][c] = (f32x4){0.f,0.f,0.f,0.f};

    #pragma unroll
    for (int h = 0; h < 2; ++h) {
        if (h) __syncthreads();
        for (int i = t; i < 1600; i += 256) {
            int cc = i / 20, kc = i - cc*20;
            int d = h*5 + (cc >> 4), oo = cc & 15;
            *(uint4*)&s_b[cc*168 + kc*8] =
                *(const uint4*)&BcT[(size_t)(d*O + o0 + oo)*KP + kc*8];
        }
        __syncthreads();

        #pragma unroll
        for (int kc = 0; kc < 5; ++kc) {
            bf16x8 af0 = *(const bf16x8*)&A[(size_t)(rowW      + ln)*KP + kc*32 + lq*8];
            bf16x8 af1 = *(const bf16x8*)&A[(size_t)(rowW + 16 + ln)*KP + kc*32 + lq*8];
            #pragma unroll
            for (int ct = 0; ct < 5; ++ct) {
                bf16x8 bf = *(const bf16x8*)&s_b[(ct*16 + ln)*168 + kc*32 + lq*8];
                acc[h][0][ct] = __builtin_amdgcn_mfma_f32_16x16x32_bf16(af0, bf, acc[h][0][ct], 0, 0, 0);
                acc[h][1][ct] = __builtin_amdgcn_mfma_f32_16x16x32_bf16(af1, bf, acc[h][1][ct], 0, 0, 0);
            }
        }
    }

    int o = o0 + ln;
    #pragma unroll
    for (int f = 0; f < 2; ++f) {
        #pragma unroll
        for (int r = 0; r < 4; ++r) {
            int row_l = w*32 + 16*f + lq*4 + r;
            size_t rowG = (size_t)rowBlock + row_l;
            int n = (int)(rowG & (NN - 1));
            int bb = (int)(rowG >> 10);
            const float* nep = &ne2[(size_t)n*ED];
            float val = biasP[(size_t)n*O + o];
            #pragma unroll
            for (int d = 0; d < 5; ++d) val += nep[d]     * acc[0][f][d][r];
            #pragma unroll
            for (int d = 0; d < 5; ++d) val += nep[5 + d] * acc[1][f][d][r];
            if (MODE == 0) {
                float sv = 1.f/(1.f + __expf(-val));
                if (o0 < 64) {
                    float zst = sv * state[rowG*DOUT + o];
                    XT1[((size_t)bb*XTR + 2 + o)*NN + n] = f2b(zst);
                } else {
                    rbuf[rowG*DOUT + (o - 64)] = sv;
                }
            } else {
                float hc = tanhf(val);
                float rg = rbuf[rowG*DOUT + o];
                float st = state[rowG*DOUT + o];
                out[rowG*DOUT + o] = rg*st + (1.f - rg)*hc;
            }
        }
    }
}

// ---------------------------------------------------------------------------
extern "C" void kernel_launch(void* const* d_in, const int* in_sizes, int n_in,
                              void* d_out, int out_size, void* d_ws, size_t ws_size,
                              hipStream_t stream)
{
    const float* x      = (const float*)d_in[0];
    const float* state  = (const float*)d_in[1];
    const float* ne0    = (const float*)d_in[2];
    const float* ne1    = (const float*)d_in[3];
    const float* ne2    = (const float*)d_in[4];
    const float* f1w1   = (const float*)d_in[5];
    const float* f1b1   = (const float*)d_in[6];
    const float* f1w2   = (const float*)d_in[7];
    const float* f1b2   = (const float*)d_in[8];
    const float* f1w3   = (const float*)d_in[9];
    const float* f1b3   = (const float*)d_in[10];
    const float* f2w1   = (const float*)d_in[11];
    const float* f2b1   = (const float*)d_in[12];
    const float* f2w2   = (const float*)d_in[13];
    const float* f2b2   = (const float*)d_in[14];
    const float* f2w3   = (const float*)d_in[15];
    const float* f2b3   = (const float*)d_in[16];
    const float* gate_w = (const float*)d_in[17];
    const float* gate_b = (const float*)d_in[18];
    const float* upd_w  = (const float*)d_in[19];
    const float* upd_b  = (const float*)d_in[20];

    unsigned short* nv1b = (unsigned short*)d_ws;
    unsigned short* nv2b = nv1b + (size_t)BB*NN*TD;
    unsigned short* XT0  = nv2b + (size_t)BB*NN*TD;
    unsigned short* XT1  = XT0  + (size_t)BB*XTR*NN;
    unsigned short* A    = XT1  + (size_t)BB*XTR*NN;
    unsigned short* BcTg = A    + (size_t)BB*NN*KP;
    unsigned short* BcTu = BcTg + (size_t)1280*KP;
    float* biasG = (float*)(BcTu + (size_t)640*KP);
    float* biasU = biasG + (size_t)NN*OG;
    float* rbuf  = biasU + (size_t)NN*OU;
    float* out   = (float*)d_out;

    k_pre<<<dim3(2608), 256, 0, stream>>>(x, state, ne0, ne1, ne2,
        f1w1, f1b1, f1w2, f1b2, f1w3, f1b3,
        f2w1, f2b1, f2w2, f2b2, f2w3, f2b3,
        gate_w, gate_b, upd_w, upd_b,
        nv1b, nv2b, XT0, XT1, BcTg, BcTu, biasG, biasU);

    k_aapply<<<dim3(512), 512, 0, stream>>>(nv1b, nv2b, XT0, A);

    k_gemm<OG,0><<<dim3(BB*NN/128, 8), 256, 0, stream>>>(A, BcTg, ne2, biasG,
                                                         state, XT1, rbuf, nullptr);

    k_aapply<<<dim3(512), 512, 0, stream>>>(nv1b, nv2b, XT1, A);

    k_gemm<OU,1><<<dim3(BB*NN/128, 4), 256, 0, stream>>>(A, BcTu, ne2, biasU,
                                                         state, nullptr, rbuf, out);
}